// Round 6
// baseline (186.163 us; speedup 1.0000x reference)
//
#include <hip/hip_runtime.h>
#include <stdint.h>

// Problem constants (from setup_inputs: B=16,H=768,W=768,N=16,P=640)
#define NIMG 16
#define IMH 768
#define IMW 768
#define NBOX 16
#define PSZ 640
#define IMG_ELEMS (IMH*IMW*3)      // 1769472
#define PATCH_ELEMS (PSZ*PSZ*3)    // 1228800
#define PATBLK 64                  // patch-sum blocks      (k_front 0..63)
#define PADBLK 64                  // patch-pad blocks      (k_front 64..127)
#define ISUM 64                    // image-sum blocks/img  (k_front 128..1151)
#define RBLK_PER_IMG 576           // render blocks per image (576*1024 = 768^2)

typedef float f4 __attribute__((ext_vector_type(4)));

// ---------------- threefry2x32 (JAX key schedule, 20 rounds) ----------------
__device__ __forceinline__ uint32_t rotl32(uint32_t v, int r){ return (v<<r)|(v>>(32-r)); }

__device__ __forceinline__ void threefry(uint32_t k0, uint32_t k1, uint32_t c0, uint32_t c1,
                                         uint32_t& o0, uint32_t& o1){
  uint32_t ks2 = k0 ^ k1 ^ 0x1BD11BDAu;
  uint32_t x0 = c0 + k0, x1 = c1 + k1;
#define TFR(r) { x0 += x1; x1 = rotl32(x1,(r)); x1 ^= x0; }
  TFR(13) TFR(15) TFR(26) TFR(6)
  x0 += k1;  x1 += ks2 + 1u;
  TFR(17) TFR(29) TFR(16) TFR(24)
  x0 += ks2; x1 += k0 + 2u;
  TFR(13) TFR(15) TFR(26) TFR(6)
  x0 += k0;  x1 += k1 + 3u;
  TFR(17) TFR(29) TFR(16) TFR(24)
  x0 += k1;  x1 += ks2 + 4u;
  TFR(13) TFR(15) TFR(26) TFR(6)
  x0 += ks2; x1 += k0 + 5u;
#undef TFR
  o0 = x0; o1 = x1;
}

__device__ __forceinline__ uint32_t rbits(uint32_t k0, uint32_t k1, uint32_t idx){
  uint32_t a, b; threefry(k0, k1, 0u, idx, a, b); return a ^ b;
}

__device__ __forceinline__ float u01(uint32_t bits){
  return __uint_as_float((bits >> 9) | 0x3f800000u) - 1.0f;
}

__device__ __forceinline__ float juniform(uint32_t k0, uint32_t k1, uint32_t idx, float mn, float mx){
  float u = u01(rbits(k0, k1, idx));
  float span = __fsub_rn(mx, mn);
  return fmaxf(mn, __fadd_rn(__fmul_rn(u, span), mn));
}

// XLA ErfInv f32 polynomial (value-path only; feeds wmul/badd)
__device__ float erfinv32(float x){
  float w = -log1pf(-x*x);
  float p;
  if (w < 5.0f){
    w = w - 2.5f;
    p = 2.81022636e-08f;
    p = fmaf(p,w, 3.43273939e-07f);
    p = fmaf(p,w,-3.5233877e-06f);
    p = fmaf(p,w,-4.39150654e-06f);
    p = fmaf(p,w, 0.00021858087f);
    p = fmaf(p,w,-0.00125372503f);
    p = fmaf(p,w,-0.00417768164f);
    p = fmaf(p,w, 0.246640727f);
    p = fmaf(p,w, 1.50140941f);
  } else {
    w = sqrtf(w) - 3.0f;
    p = -0.000200214257f;
    p = fmaf(p,w, 0.000100950558f);
    p = fmaf(p,w, 0.00134934322f);
    p = fmaf(p,w,-0.00367342844f);
    p = fmaf(p,w, 0.00573950773f);
    p = fmaf(p,w,-0.0076224613f);
    p = fmaf(p,w, 0.00943887047f);
    p = fmaf(p,w, 1.00167406f);
    p = fmaf(p,w, 2.83297682f);
  }
  return p * x;
}

// per-image wmul[3]/badd[3] into an 8-float record
__device__ __forceinline__ void compute_wb(int b, float* rec){
  uint32_t i0,i1; threefry(0u, 42u, 0u, (uint32_t)b, i0, i1);   // ikeys[b]
  uint32_t kw0,kw1; threefry(i0, i1, 0u, 0u, kw0, kw1);          // kw
  uint32_t kb0,kb1; threefry(i0, i1, 0u, 1u, kb0, kb1);          // kb
  const float lo = -0.99999994f;               // nextafter(-1,0)
  const float span = __fsub_rn(1.0f, lo);
  const float sq2 = 1.4142135623730951f;
  for (int j = 0; j < 3; j++){
    float uw = u01(rbits(kw0, kw1, (uint32_t)j));
    float rw = fmaxf(lo, __fadd_rn(__fmul_rn(uw, span), lo));
    float nw = __fmul_rn(sq2, erfinv32(rw));
    rec[j] = __fadd_rn(0.5f, __fmul_rn(0.1f, nw));               // wmul
    float ub = u01(rbits(kb0, kb1, (uint32_t)j));
    float rb = fmaxf(lo, __fadd_rn(__fmul_rn(ub, span), lo));
    float nb = __fmul_rn(sq2, erfinv32(rb));
    rec[3+j] = __fmul_rn(0.01f, nb);                             // badd
  }
  rec[6] = 0.0f; rec[7] = 0.0f;
}

// ---------------- K1: fused patchsum16 | patch-pad | imgsum (read-only) -----
__global__ __launch_bounds__(256) void k_front(const float* __restrict__ img,
                                               const float* __restrict__ patch,
                                               double* __restrict__ imgpart,
                                               double* __restrict__ patpart,
                                               f4* __restrict__ pad4, int do_pad){
  if (blockIdx.x < PATBLK){
    // ---- patch path: seed wb in-block, 16 adjusted sums ----
    __shared__ float wl[NIMG*8];
    if (threadIdx.x < NIMG) compute_wb(threadIdx.x, &wl[threadIdx.x*8]);
    __syncthreads();
    double s[NIMG];
    #pragma unroll
    for (int im = 0; im < NIMG; im++) s[im] = 0.0;
    const f4* p4 = (const f4*)patch;
    const int N4 = PATCH_ELEMS/4;     // 307200
    for (int i = blockIdx.x*256 + threadIdx.x; i < N4; i += PATBLK*256){
      f4 v = p4[i];
      int c = (i << 2) % 3;
      #pragma unroll
      for (int q = 0; q < 4; q++){
        float pv = v[q];
        #pragma unroll
        for (int im = 0; im < NIMG; im++){
          float t = __fadd_rn(__fmul_rn(wl[im*8 + c], pv), wl[im*8 + 3 + c]);
          t = fminf(fmaxf(t, -1.0f), 1.0f);
          s[im] += (double)t;
        }
        c = (c == 2) ? 0 : c + 1;
      }
    }
    #pragma unroll
    for (int im = 0; im < NIMG; im++)
      for (int o = 32; o > 0; o >>= 1) s[im] += __shfl_down(s[im], o);
    __shared__ double red[4][NIMG];
    if ((threadIdx.x & 63) == 0){
      int w = threadIdx.x >> 6;
      #pragma unroll
      for (int im = 0; im < NIMG; im++) red[w][im] = s[im];
    }
    __syncthreads();
    if (threadIdx.x < NIMG){
      double t = red[0][threadIdx.x] + red[1][threadIdx.x] + red[2][threadIdx.x] + red[3][threadIdx.x];
      patpart[threadIdx.x*PATBLK + blockIdx.x] = t;
    }
  } else if (blockIdx.x < PATBLK + PADBLK){
    // ---- patch padding path: {r,g,b} -> 16B texels in ws ----
    if (!do_pad) return;
    int pb = blockIdx.x - PATBLK;
    const f4* src = (const f4*)patch;
    const int NG = PSZ*PSZ/4;         // 102400 groups of 4 texels (=3 f4 reads)
    for (int g = pb*256 + threadIdx.x; g < NG; g += PADBLK*256){
      f4 a = src[g*3+0], b2 = src[g*3+1], c2 = src[g*3+2];
      f4 t0 = {a.x,  a.y,  a.z,  0.0f};
      f4 t1 = {a.w,  b2.x, b2.y, 0.0f};
      f4 t2 = {b2.z, b2.w, c2.x, 0.0f};
      f4 t3 = {c2.y, c2.z, c2.w, 0.0f};
      pad4[g*4+0] = t0; pad4[g*4+1] = t1; pad4[g*4+2] = t2; pad4[g*4+3] = t3;
    }
  } else {
    // ---- image-sum path (read-only) ----
    int bi = blockIdx.x - (PATBLK + PADBLK);
    int b = bi >> 6;                  // / ISUM
    int j = bi & (ISUM-1);
    const f4* src = (const f4*)(img + (size_t)b * IMG_ELEMS);
    const int N4 = IMG_ELEMS/4;       // 442368 ; /(64*256) = 27 exact
    f4 fs = {0.0f, 0.0f, 0.0f, 0.0f};
    for (int i = j*256 + threadIdx.x; i < N4; i += ISUM*256){
      f4 v = src[i];
      fs += v;
    }
    double s = ((double)fs.x + (double)fs.y) + ((double)fs.z + (double)fs.w);
    for (int o = 32; o > 0; o >>= 1) s += __shfl_down(s, o);
    __shared__ double sm[4];
    if ((threadIdx.x & 63) == 0) sm[threadIdx.x >> 6] = s;
    __syncthreads();
    if (threadIdx.x == 0) imgpart[b*ISUM + j] = sm[0]+sm[1]+sm[2]+sm[3];
  }
}

// ---------------- K2: finalize means/shift/wb + box params + row masks ------
// box param layout (16 floats): 0:y0 1:x0 2:d 3:ph 4:top 5:c 6:ca 7:sa
//                               8:sres 9:delta 10:noisek0 11:noisek1 12:valid 13:ph-1
__global__ __launch_bounds__(256) void k_final(const double* __restrict__ imgpart,
                        const double* __restrict__ patpart,
                        float* __restrict__ shift, float* __restrict__ wbg,
                        float* __restrict__ boxp, uint32_t* __restrict__ masks,
                        const float* __restrict__ boxes, const float* __restrict__ scale){
  int t = threadIdx.x;
  __shared__ uint32_t rm[NIMG*IMH];     // 48 KB row-mask
  for (int i = t; i < NIMG*IMH; i += 256) rm[i] = 0u;

  // parallel partial reduction: 16 lanes per image
  {
    int im = t >> 4, l = t & 15;
    double si = 0.0, sp = 0.0;
    #pragma unroll
    for (int j = 0; j < ISUM/16; j++) si += imgpart[im*ISUM + l + j*16];
    #pragma unroll
    for (int j = 0; j < PATBLK/16; j++) sp += patpart[im*PATBLK + l + j*16];
    #pragma unroll
    for (int o = 8; o > 0; o >>= 1){ si += __shfl_down(si, o); sp += __shfl_down(sp, o); }
    if (l == 0){
      float mi = (float)(si / (double)IMG_ELEMS);
      float mp = (float)(sp / (double)PATCH_ELEMS);
      shift[im] = __fsub_rn(mi, mp);
      compute_wb(im, &wbg[im*8]);
    }
  }
  __syncthreads();

  {
    int b = t / NBOX, i = t % NBOX;
    uint32_t i0,i1;  threefry(0u, 42u, 0u, (uint32_t)b, i0, i1);     // ikeys[b]
    uint32_t kx0,kx1; threefry(i0, i1, 0u, 2u, kx0, kx1);            // kboxes
    uint32_t bk0,bk1; threefry(kx0, kx1, 0u, (uint32_t)i, bk0, bk1); // bkeys[i]
    uint32_t K1a,K1b,K2a,K2b,K3a,K3b,K4a,K4b,K5a,K5b;
    threefry(bk0,bk1,0u,0u,K1a,K1b);  // k1: oy jitter
    threefry(bk0,bk1,0u,1u,K2a,K2b);  // k2: ox jitter
    threefry(bk0,bk1,0u,2u,K3a,K3b);  // k3: angle
    threefry(bk0,bk1,0u,3u,K4a,K4b);  // k4: noise field
    threefry(bk0,bk1,0u,4u,K5a,K5b);  // k5: delta

    const float* bx = boxes + (size_t)t*4;
    float ymin = bx[0], xmin = bx[1], ymax = bx[2], xmax = bx[3];
    float bh = __fsub_rn(ymax, ymin);
    float bw = __fsub_rn(xmax, xmin);
    float longer = fmaxf(bh, bw);
    float sc = scale[0];
    float psize = floorf(__fmul_rn(longer, sc));
    float diag = fminf(__fmul_rn(1.4142135623730951f, psize), 768.0f);

    float mny = __fdiv_rn(__fmul_rn(-0.2f, bh), 2.0f);
    float mxy = __fdiv_rn(__fmul_rn( 0.2f, bh), 2.0f);
    float r1 = juniform(K1a, K1b, 0u, mny, mxy);
    float oy = __fadd_rn(__fadd_rn(ymin, __fdiv_rn(bh, 2.0f)), r1);
    float mnx = __fdiv_rn(__fmul_rn(-0.2f, bw), 2.0f);
    float mxx = __fdiv_rn(__fmul_rn( 0.2f, bw), 2.0f);
    float r2 = juniform(K2a, K2b, 0u, mnx, mxx);
    float ox = __fadd_rn(__fadd_rn(xmin, __fdiv_rn(bw, 2.0f)), r2);

    float hd = __fdiv_rn(diag, 2.0f);
    float y0 = fmaxf(__fsub_rn(oy, hd), 0.0f);
    float x0 = fmaxf(__fsub_rn(ox, hd), 0.0f);
    if (__fadd_rn(y0, diag) > 768.0f) y0 = __fsub_rn(768.0f, diag);
    if (__fadd_rn(x0, diag) > 768.0f) x0 = __fsub_rn(768.0f, diag);
    y0 = floorf(y0);
    x0 = floorf(x0);
    float d  = floorf(diag);
    float ph = psize;
    float top = floorf(__fdiv_rn(__fsub_rn(d, ph), 2.0f));

    const float A20 = 0.3490658503988659f;   // 20 deg in rad, f32
    float ang = juniform(K3a, K3b, 0u, -A20, A20);
    double da = (double)ang;
    float ca = (float)cos(da);
    float sa = (float)sin(da);
    float delta = juniform(K5a, K5b, 0u, -0.3f, 0.3f);
    float valid = (__fmul_rn(ph, ph) > 4.0f) ? 1.0f : 0.0f;
    float cc  = __fdiv_rn(__fsub_rn(d, 1.0f), 2.0f);
    float sres = __fdiv_rn(640.0f, ph);      // P / ph

    float* o = boxp + t*16;
    o[0]=y0; o[1]=x0; o[2]=d; o[3]=ph; o[4]=top; o[5]=cc; o[6]=ca; o[7]=sa;
    o[8]=sres; o[9]=delta;
    o[10]=__uint_as_float(K4a); o[11]=__uint_as_float(K4b);
    o[12]=valid; o[13]=__fsub_rn(ph, 1.0f); o[14]=0.0f; o[15]=0.0f;

    // row-mask: mark rows [y0, y0+d) for this (image, box)
    if (valid != 0.0f){
      int y0i = (int)y0, di = (int)d;
      uint32_t bit = 1u << i;
      for (int y = y0i; y < y0i + di; y++)
        atomicOr(&rm[b*IMH + y], bit);
    }
  }
  __syncthreads();
  for (int i = t; i < NIMG*IMH; i += 256) masks[i] = rm[i];
}

// ---------------- K3: streaming full-image render (copy fused) --------------
template<int USEPAD>
__global__ __launch_bounds__(256) void k_render4(
    const float* __restrict__ img, const float* __restrict__ patch,
    const f4* __restrict__ pad4, const float* __restrict__ wbg,
    const float* __restrict__ shiftg, const float* __restrict__ boxp,
    const uint32_t* __restrict__ masks, float* __restrict__ out)
{
  int b   = blockIdx.x / RBLK_PER_IMG;
  int blk = blockIdx.x - b*RBLK_PER_IMG;

  __shared__ float sp[NBOX*16];
  __shared__ float wl[8];
  __shared__ float shl;
  sp[threadIdx.x] = boxp[b*NBOX*16 + threadIdx.x];
  if (threadIdx.x < 8) wl[threadIdx.x] = wbg[b*8 + threadIdx.x];
  if (threadIdx.x == 0) shl = shiftg[b];
  __syncthreads();

  int pixbase = blk*1024 + (int)threadIdx.x*4;       // 4 consecutive pixels
  int y = pixbase / IMW;                              // 768%4==0 -> same row
  int xb = pixbase - y*IMW;
  float yf = (float)y;

  const f4* src = (const f4*)(img + (size_t)b*IMG_ELEMS);
  f4* dst = (f4*)(out + (size_t)b*IMG_ELEMS);
  int vbase = blk*768 + (int)threadIdx.x*3;           // 3 f4 per thread
  f4 A = src[vbase+0], Bv = src[vbase+1], Cv = src[vbase+2];
  float arr[12];
  arr[0]=A.x; arr[1]=A.y; arr[2]=A.z; arr[3]=A.w;
  arr[4]=Bv.x; arr[5]=Bv.y; arr[6]=Bv.z; arr[7]=Bv.w;
  arr[8]=Cv.x; arr[9]=Cv.y; arr[10]=Cv.z; arr[11]=Cv.w;

  uint32_t m0 = masks[b*IMH + y];

  if (m0){
    #pragma unroll
    for (int g = 0; g < 4; g++){
      float xf = (float)(xb + g);
      uint32_t m = m0;
      bool done = false;
      while (m && !done){
        int j = 31 - __clz(m);
        m &= ~(1u << j);
        const float* bq = &sp[j*16];
        float v2 = __fsub_rn(xf, bq[1]);
        if (!(v2 >= 0.0f && v2 < bq[2])) continue;
        float u2 = __fsub_rn(yf, bq[0]);
        float cc2 = bq[5];
        float um2 = __fsub_rn(u2, cc2), vm2 = __fsub_rn(v2, cc2);
        float iu2 = __fsub_rn(__fadd_rn(cc2, __fmul_rn(bq[6], um2)), __fmul_rn(bq[7], vm2));
        float iv2 = __fadd_rn(__fadd_rn(cc2, __fmul_rn(bq[7], um2)), __fmul_rn(bq[6], vm2));
        float py = __fsub_rn(iu2, bq[4]), px = __fsub_rn(iv2, bq[4]);
        if (!(py >= 0.0f && py <= bq[13] && px >= 0.0f && px <= bq[13])) continue;
        // winner j: render this pixel
        done = true;
        float sres = bq[8], delta = bq[9];
        uint32_t n0 = __float_as_uint(bq[10]);
        uint32_t n1 = __float_as_uint(bq[11]);
        float sy = __fsub_rn(__fmul_rn(__fadd_rn(py, 0.5f), sres), 0.5f);
        float sx = __fsub_rn(__fmul_rn(__fadd_rn(px, 0.5f), sres), 0.5f);
        float fy = floorf(sy), fx = floorf(sx);
        float wy = __fsub_rn(sy, fy), wx = __fsub_rn(sx, fx);
        int y0t = (int)fminf(fmaxf(fy, 0.0f), 639.0f);
        int y1t = (int)fminf(fmaxf(__fadd_rn(fy, 1.0f), 0.0f), 639.0f);
        int x0t = (int)fminf(fmaxf(fx, 0.0f), 639.0f);
        int x1t = (int)fminf(fmaxf(__fadd_rn(fx, 1.0f), 0.0f), 639.0f);
        float w00 = (1.0f-wy)*(1.0f-wx), w01 = (1.0f-wy)*wx;
        float w10 = wy*(1.0f-wx),        w11 = wy*wx;
        f4 p00, p01, p10, p11;
        int i00, i01, i10, i11;
        if constexpr (USEPAD){
          p00 = pad4[y0t*PSZ + x0t]; p01 = pad4[y0t*PSZ + x1t];
          p10 = pad4[y1t*PSZ + x0t]; p11 = pad4[y1t*PSZ + x1t];
          i00 = i01 = i10 = i11 = 0;
        } else {
          i00 = (y0t*PSZ + x0t)*3; i01 = (y0t*PSZ + x1t)*3;
          i10 = (y1t*PSZ + x0t)*3; i11 = (y1t*PSZ + x1t)*3;
        }
        int pix = pixbase + g;
        #pragma unroll
        for (int c = 0; c < 3; c++){
          float wm = wl[c], bd = wl[3+c];
          float t00, t01, t10, t11;
          if constexpr (USEPAD){ t00 = p00[c]; t01 = p01[c]; t10 = p10[c]; t11 = p11[c]; }
          else { t00 = patch[i00+c]; t01 = patch[i01+c]; t10 = patch[i10+c]; t11 = patch[i11+c]; }
          float v00 = fminf(fmaxf(__fadd_rn(__fmul_rn(wm, t00), bd), -1.0f), 1.0f);
          v00 = fminf(fmaxf(__fadd_rn(v00, shl), -1.0f), 1.0f);
          float v01 = fminf(fmaxf(__fadd_rn(__fmul_rn(wm, t01), bd), -1.0f), 1.0f);
          v01 = fminf(fmaxf(__fadd_rn(v01, shl), -1.0f), 1.0f);
          float v10 = fminf(fmaxf(__fadd_rn(__fmul_rn(wm, t10), bd), -1.0f), 1.0f);
          v10 = fminf(fmaxf(__fadd_rn(v10, shl), -1.0f), 1.0f);
          float v11 = fminf(fmaxf(__fadd_rn(__fmul_rn(wm, t11), bd), -1.0f), 1.0f);
          v11 = fminf(fmaxf(__fadd_rn(v11, shl), -1.0f), 1.0f);
          float val = v00*w00 + v01*w01 + v10*w10 + v11*w11;
          float un = u01(rbits(n0, n1, (uint32_t)(pix*3 + c)));
          float span = __fsub_rn(0.01f, -0.01f);
          float nz = fmaxf(-0.01f, __fadd_rn(__fmul_rn(un, span), -0.01f));
          val = __fadd_rn(__fadd_rn(val, nz), delta);
          arr[g*3 + c] = fminf(fmaxf(val, -1.0f), 1.0f);
        }
      }
    }
  }

  f4 o0 = {arr[0], arr[1], arr[2], arr[3]};
  f4 o1 = {arr[4], arr[5], arr[6], arr[7]};
  f4 o2 = {arr[8], arr[9], arr[10], arr[11]};
  __builtin_nontemporal_store(o0, dst + vbase + 0);
  __builtin_nontemporal_store(o1, dst + vbase + 1);
  __builtin_nontemporal_store(o2, dst + vbase + 2);
}

// ---------------- host launch ----------------
extern "C" void kernel_launch(void* const* d_in, const int* in_sizes, int n_in,
                              void* d_out, int out_size, void* d_ws, size_t ws_size,
                              hipStream_t stream){
  (void)in_sizes; (void)n_in; (void)out_size;
  const float* images = (const float*)d_in[0];
  const float* boxes  = (const float*)d_in[1];
  const float* patch  = (const float*)d_in[2];
  const float* scale  = (const float*)d_in[3];
  float* out = (float*)d_out;

  char* ws = (char*)d_ws;
  double*   imgpart = (double*)(ws);              // 16*64*8 = 8192 B
  double*   patpart = (double*)(ws + 8192);       // 8192 B
  float*    wb      = (float*)(ws + 16384);       // 512 B
  float*    shift   = (float*)(ws + 16896);       // 64 B
  float*    boxp    = (float*)(ws + 17408);       // 16384 B
  uint32_t* masks   = (uint32_t*)(ws + 33792);    // 16*768*4 = 49152 B
  f4*       pad4    = (f4*)(ws + 98304);          // 640*640*16 = 6553600 B

  size_t need = 98304 + (size_t)PSZ*PSZ*16;
  int do_pad = (ws_size >= need) ? 1 : 0;

  hipLaunchKernelGGL(k_front, dim3(PATBLK + PADBLK + NIMG*ISUM), dim3(256), 0, stream,
                     images, patch, imgpart, patpart, pad4, do_pad);
  hipLaunchKernelGGL(k_final, dim3(1), dim3(256), 0, stream,
                     imgpart, patpart, shift, wb, boxp, masks, boxes, scale);
  if (do_pad)
    hipLaunchKernelGGL(k_render4<1>, dim3(NIMG*RBLK_PER_IMG), dim3(256), 0, stream,
                       images, patch, pad4, wb, shift, boxp, masks, out);
  else
    hipLaunchKernelGGL(k_render4<0>, dim3(NIMG*RBLK_PER_IMG), dim3(256), 0, stream,
                       images, patch, pad4, wb, shift, boxp, masks, out);
}

// Round 7
// 114.491 us; speedup vs baseline: 1.6260x; 1.6260x over previous
//
#include <hip/hip_runtime.h>
#include <stdint.h>

// Problem constants (from setup_inputs: B=16,H=768,W=768,N=16,P=640)
#define NIMG 16
#define IMH 768
#define IMW 768
#define NBOX 16
#define PSZ 640
#define IMG_ELEMS (IMH*IMW*3)      // 1769472
#define PATCH_ELEMS (PSZ*PSZ*3)    // 1228800
#define PATBLK 64                  // patch-sum blocks      (k_front 0..63)
#define PADBLK 64                  // patch-pad blocks      (k_front 64..127)
#define ISUM 64                    // copy blocks per image (k_front 128..)
#define RENDER_BLKS 4096

typedef float f4 __attribute__((ext_vector_type(4)));

// ---------------- threefry2x32 (JAX key schedule, 20 rounds) ----------------
__device__ __forceinline__ uint32_t rotl32(uint32_t v, int r){ return (v<<r)|(v>>(32-r)); }

__device__ __forceinline__ void threefry(uint32_t k0, uint32_t k1, uint32_t c0, uint32_t c1,
                                         uint32_t& o0, uint32_t& o1){
  uint32_t ks2 = k0 ^ k1 ^ 0x1BD11BDAu;
  uint32_t x0 = c0 + k0, x1 = c1 + k1;
#define TFR(r) { x0 += x1; x1 = rotl32(x1,(r)); x1 ^= x0; }
  TFR(13) TFR(15) TFR(26) TFR(6)
  x0 += k1;  x1 += ks2 + 1u;
  TFR(17) TFR(29) TFR(16) TFR(24)
  x0 += ks2; x1 += k0 + 2u;
  TFR(13) TFR(15) TFR(26) TFR(6)
  x0 += k0;  x1 += k1 + 3u;
  TFR(17) TFR(29) TFR(16) TFR(24)
  x0 += k1;  x1 += ks2 + 4u;
  TFR(13) TFR(15) TFR(26) TFR(6)
  x0 += ks2; x1 += k0 + 5u;
#undef TFR
  o0 = x0; o1 = x1;
}

__device__ __forceinline__ uint32_t rbits(uint32_t k0, uint32_t k1, uint32_t idx){
  uint32_t a, b; threefry(k0, k1, 0u, idx, a, b); return a ^ b;
}

__device__ __forceinline__ float u01(uint32_t bits){
  return __uint_as_float((bits >> 9) | 0x3f800000u) - 1.0f;
}

__device__ __forceinline__ float juniform(uint32_t k0, uint32_t k1, uint32_t idx, float mn, float mx){
  float u = u01(rbits(k0, k1, idx));
  float span = __fsub_rn(mx, mn);
  return fmaxf(mn, __fadd_rn(__fmul_rn(u, span), mn));
}

// XLA ErfInv f32 polynomial (value-path only; feeds wmul/badd)
__device__ float erfinv32(float x){
  float w = -log1pf(-x*x);
  float p;
  if (w < 5.0f){
    w = w - 2.5f;
    p = 2.81022636e-08f;
    p = fmaf(p,w, 3.43273939e-07f);
    p = fmaf(p,w,-3.5233877e-06f);
    p = fmaf(p,w,-4.39150654e-06f);
    p = fmaf(p,w, 0.00021858087f);
    p = fmaf(p,w,-0.00125372503f);
    p = fmaf(p,w,-0.00417768164f);
    p = fmaf(p,w, 0.246640727f);
    p = fmaf(p,w, 1.50140941f);
  } else {
    w = sqrtf(w) - 3.0f;
    p = -0.000200214257f;
    p = fmaf(p,w, 0.000100950558f);
    p = fmaf(p,w, 0.00134934322f);
    p = fmaf(p,w,-0.00367342844f);
    p = fmaf(p,w, 0.00573950773f);
    p = fmaf(p,w,-0.0076224613f);
    p = fmaf(p,w, 0.00943887047f);
    p = fmaf(p,w, 1.00167406f);
    p = fmaf(p,w, 2.83297682f);
  }
  return p * x;
}

// per-image wmul[3]/badd[3] into an 8-float record
__device__ __forceinline__ void compute_wb(int b, float* rec){
  uint32_t i0,i1; threefry(0u, 42u, 0u, (uint32_t)b, i0, i1);   // ikeys[b]
  uint32_t kw0,kw1; threefry(i0, i1, 0u, 0u, kw0, kw1);          // kw
  uint32_t kb0,kb1; threefry(i0, i1, 0u, 1u, kb0, kb1);          // kb
  const float lo = -0.99999994f;               // nextafter(-1,0)
  const float span = __fsub_rn(1.0f, lo);
  const float sq2 = 1.4142135623730951f;
  for (int j = 0; j < 3; j++){
    float uw = u01(rbits(kw0, kw1, (uint32_t)j));
    float rw = fmaxf(lo, __fadd_rn(__fmul_rn(uw, span), lo));
    float nw = __fmul_rn(sq2, erfinv32(rw));
    rec[j] = __fadd_rn(0.5f, __fmul_rn(0.1f, nw));               // wmul
    float ub = u01(rbits(kb0, kb1, (uint32_t)j));
    float rb = fmaxf(lo, __fadd_rn(__fmul_rn(ub, span), lo));
    float nb = __fmul_rn(sq2, erfinv32(rb));
    rec[3+j] = __fmul_rn(0.01f, nb);                             // badd
  }
  rec[6] = 0.0f; rec[7] = 0.0f;
}

// ---------------- K1: fused patchsum16 | patch-pad | copy+imgsum (ILP=8) ----
__global__ __launch_bounds__(256) void k_front(const float* __restrict__ img,
                                               const float* __restrict__ patch,
                                               float* __restrict__ out,
                                               double* __restrict__ imgpart,
                                               double* __restrict__ patpart,
                                               f4* __restrict__ pad4, int do_pad){
  if (blockIdx.x < PATBLK){
    // ---- patch path: seed wb in-block, 16 adjusted sums ----
    __shared__ float wl[NIMG*8];
    if (threadIdx.x < NIMG) compute_wb(threadIdx.x, &wl[threadIdx.x*8]);
    __syncthreads();
    double s[NIMG];
    #pragma unroll
    for (int im = 0; im < NIMG; im++) s[im] = 0.0;
    const f4* p4 = (const f4*)patch;
    const int N4 = PATCH_ELEMS/4;     // 307200
    for (int i = blockIdx.x*256 + threadIdx.x; i < N4; i += PATBLK*256){
      f4 v = p4[i];
      int c = (i << 2) % 3;
      #pragma unroll
      for (int q = 0; q < 4; q++){
        float pv = v[q];
        #pragma unroll
        for (int im = 0; im < NIMG; im++){
          float t = __fadd_rn(__fmul_rn(wl[im*8 + c], pv), wl[im*8 + 3 + c]);
          t = fminf(fmaxf(t, -1.0f), 1.0f);
          s[im] += (double)t;
        }
        c = (c == 2) ? 0 : c + 1;
      }
    }
    #pragma unroll
    for (int im = 0; im < NIMG; im++)
      for (int o = 32; o > 0; o >>= 1) s[im] += __shfl_down(s[im], o);
    __shared__ double red[4][NIMG];
    if ((threadIdx.x & 63) == 0){
      int w = threadIdx.x >> 6;
      #pragma unroll
      for (int im = 0; im < NIMG; im++) red[w][im] = s[im];
    }
    __syncthreads();
    if (threadIdx.x < NIMG){
      double t = red[0][threadIdx.x] + red[1][threadIdx.x] + red[2][threadIdx.x] + red[3][threadIdx.x];
      patpart[threadIdx.x*PATBLK + blockIdx.x] = t;
    }
  } else if (blockIdx.x < PATBLK + PADBLK){
    // ---- patch padding path: {r,g,b} -> 16B texels in ws ----
    if (!do_pad) return;
    int pb = blockIdx.x - PATBLK;
    const f4* src = (const f4*)patch;
    const int NG = PSZ*PSZ/4;         // 102400 groups of 4 texels (=3 f4 reads)
    for (int g = pb*256 + threadIdx.x; g < NG; g += PADBLK*256){
      f4 a = src[g*3+0], b2 = src[g*3+1], c2 = src[g*3+2];
      f4 t0 = {a.x,  a.y,  a.z,  0.0f};
      f4 t1 = {a.w,  b2.x, b2.y, 0.0f};
      f4 t2 = {b2.z, b2.w, c2.x, 0.0f};
      f4 t3 = {c2.y, c2.z, c2.w, 0.0f};
      pad4[g*4+0] = t0; pad4[g*4+1] = t1; pad4[g*4+2] = t2; pad4[g*4+3] = t3;
    }
  } else {
    // ---- copy + image-sum path, 8 independent loads in flight ----
    int bi = blockIdx.x - (PATBLK + PADBLK);
    int b = bi >> 6;                  // / ISUM
    int j = bi & (ISUM-1);
    const f4* src = (const f4*)(img + (size_t)b * IMG_ELEMS);
    f4* dst = (f4*)(out + (size_t)b * IMG_ELEMS);
    const int STRIDE = ISUM*256;      // 16384 ; N4 = 442368 = 27*16384
    int i = j*256 + (int)threadIdx.x;
    f4 acc = {0.0f, 0.0f, 0.0f, 0.0f};
    #pragma unroll 1
    for (int g = 0; g < 3; ++g){
      f4 v0 = __builtin_nontemporal_load(src + i + 0*STRIDE);
      f4 v1 = __builtin_nontemporal_load(src + i + 1*STRIDE);
      f4 v2 = __builtin_nontemporal_load(src + i + 2*STRIDE);
      f4 v3 = __builtin_nontemporal_load(src + i + 3*STRIDE);
      f4 v4 = __builtin_nontemporal_load(src + i + 4*STRIDE);
      f4 v5 = __builtin_nontemporal_load(src + i + 5*STRIDE);
      f4 v6 = __builtin_nontemporal_load(src + i + 6*STRIDE);
      f4 v7 = __builtin_nontemporal_load(src + i + 7*STRIDE);
      __builtin_nontemporal_store(v0, dst + i + 0*STRIDE);
      __builtin_nontemporal_store(v1, dst + i + 1*STRIDE);
      __builtin_nontemporal_store(v2, dst + i + 2*STRIDE);
      __builtin_nontemporal_store(v3, dst + i + 3*STRIDE);
      __builtin_nontemporal_store(v4, dst + i + 4*STRIDE);
      __builtin_nontemporal_store(v5, dst + i + 5*STRIDE);
      __builtin_nontemporal_store(v6, dst + i + 6*STRIDE);
      __builtin_nontemporal_store(v7, dst + i + 7*STRIDE);
      acc += v0; acc += v1; acc += v2; acc += v3;
      acc += v4; acc += v5; acc += v6; acc += v7;
      i += 8*STRIDE;
    }
    {   // tail: 3 more (27 = 3*8 + 3)
      f4 v0 = __builtin_nontemporal_load(src + i + 0*STRIDE);
      f4 v1 = __builtin_nontemporal_load(src + i + 1*STRIDE);
      f4 v2 = __builtin_nontemporal_load(src + i + 2*STRIDE);
      __builtin_nontemporal_store(v0, dst + i + 0*STRIDE);
      __builtin_nontemporal_store(v1, dst + i + 1*STRIDE);
      __builtin_nontemporal_store(v2, dst + i + 2*STRIDE);
      acc += v0; acc += v1; acc += v2;
    }
    double s = ((double)acc.x + (double)acc.y) + ((double)acc.z + (double)acc.w);
    for (int o = 32; o > 0; o >>= 1) s += __shfl_down(s, o);
    __shared__ double sm[4];
    if ((threadIdx.x & 63) == 0) sm[threadIdx.x >> 6] = s;
    __syncthreads();
    if (threadIdx.x == 0) imgpart[b*ISUM + j] = sm[0]+sm[1]+sm[2]+sm[3];
  }
}

// ---------------- K2: finalize means/shift/wb + box params + overlap + scan -
// box param layout (16 floats): 0:y0 1:x0 2:d 3:ph 4:top 5:c 6:ca 7:sa
//                               8:sres 9:delta 10:noisek0 11:noisek1 12:valid 13:ph-1 14:omask
__global__ __launch_bounds__(256) void k_final(const double* __restrict__ imgpart,
                        const double* __restrict__ patpart,
                        float* __restrict__ shift, float* __restrict__ wbg,
                        float* __restrict__ boxp, int* __restrict__ chunkoff,
                        const float* __restrict__ boxes, const float* __restrict__ scale){
  int t = threadIdx.x;
  // parallel partial reduction: 16 lanes per image
  {
    int im = t >> 4, l = t & 15;
    double si = 0.0, sp = 0.0;
    #pragma unroll
    for (int j = 0; j < ISUM/16; j++) si += imgpart[im*ISUM + l + j*16];
    #pragma unroll
    for (int j = 0; j < PATBLK/16; j++) sp += patpart[im*PATBLK + l + j*16];
    #pragma unroll
    for (int o = 8; o > 0; o >>= 1){ si += __shfl_down(si, o); sp += __shfl_down(sp, o); }
    if (l == 0){
      float mi = (float)(si / (double)IMG_ELEMS);
      float mp = (float)(sp / (double)PATCH_ELEMS);
      shift[im] = __fsub_rn(mi, mp);
      compute_wb(im, &wbg[im*8]);
    }
  }

  __shared__ float sy0[256], sx0[256], sd[256], sv[256];
  int nch = 0;
  float* o = boxp + t*16;
  {
    int b = t / NBOX, i = t % NBOX;
    uint32_t i0,i1;  threefry(0u, 42u, 0u, (uint32_t)b, i0, i1);     // ikeys[b]
    uint32_t kx0,kx1; threefry(i0, i1, 0u, 2u, kx0, kx1);            // kboxes
    uint32_t bk0,bk1; threefry(kx0, kx1, 0u, (uint32_t)i, bk0, bk1); // bkeys[i]
    uint32_t K1a,K1b,K2a,K2b,K3a,K3b,K4a,K4b,K5a,K5b;
    threefry(bk0,bk1,0u,0u,K1a,K1b);  // k1: oy jitter
    threefry(bk0,bk1,0u,1u,K2a,K2b);  // k2: ox jitter
    threefry(bk0,bk1,0u,2u,K3a,K3b);  // k3: angle
    threefry(bk0,bk1,0u,3u,K4a,K4b);  // k4: noise field
    threefry(bk0,bk1,0u,4u,K5a,K5b);  // k5: delta

    const float* bx = boxes + (size_t)t*4;
    float ymin = bx[0], xmin = bx[1], ymax = bx[2], xmax = bx[3];
    float bh = __fsub_rn(ymax, ymin);
    float bw = __fsub_rn(xmax, xmin);
    float longer = fmaxf(bh, bw);
    float sc = scale[0];
    float psize = floorf(__fmul_rn(longer, sc));
    float diag = fminf(__fmul_rn(1.4142135623730951f, psize), 768.0f);

    float mny = __fdiv_rn(__fmul_rn(-0.2f, bh), 2.0f);
    float mxy = __fdiv_rn(__fmul_rn( 0.2f, bh), 2.0f);
    float r1 = juniform(K1a, K1b, 0u, mny, mxy);
    float oy = __fadd_rn(__fadd_rn(ymin, __fdiv_rn(bh, 2.0f)), r1);
    float mnx = __fdiv_rn(__fmul_rn(-0.2f, bw), 2.0f);
    float mxx = __fdiv_rn(__fmul_rn( 0.2f, bw), 2.0f);
    float r2 = juniform(K2a, K2b, 0u, mnx, mxx);
    float ox = __fadd_rn(__fadd_rn(xmin, __fdiv_rn(bw, 2.0f)), r2);

    float hd = __fdiv_rn(diag, 2.0f);
    float y0 = fmaxf(__fsub_rn(oy, hd), 0.0f);
    float x0 = fmaxf(__fsub_rn(ox, hd), 0.0f);
    if (__fadd_rn(y0, diag) > 768.0f) y0 = __fsub_rn(768.0f, diag);
    if (__fadd_rn(x0, diag) > 768.0f) x0 = __fsub_rn(768.0f, diag);
    y0 = floorf(y0);
    x0 = floorf(x0);
    float d  = floorf(diag);
    float ph = psize;
    float top = floorf(__fdiv_rn(__fsub_rn(d, ph), 2.0f));

    const float A20 = 0.3490658503988659f;   // 20 deg in rad, f32
    float ang = juniform(K3a, K3b, 0u, -A20, A20);
    double da = (double)ang;
    float ca = (float)cos(da);
    float sa = (float)sin(da);
    float delta = juniform(K5a, K5b, 0u, -0.3f, 0.3f);
    float valid = (__fmul_rn(ph, ph) > 4.0f) ? 1.0f : 0.0f;
    float cc  = __fdiv_rn(__fsub_rn(d, 1.0f), 2.0f);
    float sres = __fdiv_rn(640.0f, ph);      // P / ph

    o[0]=y0; o[1]=x0; o[2]=d; o[3]=ph; o[4]=top; o[5]=cc; o[6]=ca; o[7]=sa;
    o[8]=sres; o[9]=delta;
    o[10]=__uint_as_float(K4a); o[11]=__uint_as_float(K4b);
    o[12]=valid; o[13]=__fsub_rn(ph, 1.0f); o[15]=0.0f;

    sy0[t]=y0; sx0[t]=x0; sd[t]=d; sv[t]=valid;
    if (valid != 0.0f){
      int di = (int)d;
      nch = (di*di + 255) >> 8;
    }
  }
  __syncthreads();
  // overlap mask: boxes j>i of same image whose window rect intersects ours
  {
    int i = t & 15, base = t & ~15;
    uint32_t om = 0u;
    for (int j = i+1; j < NBOX; j++){
      int tj = base + j;
      if (sv[tj] == 0.0f) continue;
      if (sy0[t] < sy0[tj]+sd[tj] && sy0[tj] < sy0[t]+sd[t] &&
          sx0[t] < sx0[tj]+sd[tj] && sx0[tj] < sx0[t]+sd[t]) om |= (1u << j);
    }
    o[14] = __uint_as_float(om);
  }

  // block-wide inclusive scan of nch over 256 threads
  __shared__ int scan[256];
  scan[t] = nch; __syncthreads();
  for (int off = 1; off < 256; off <<= 1){
    int v = (t >= off) ? scan[t-off] : 0;
    __syncthreads();
    scan[t] += v;
    __syncthreads();
  }
  if (t == 0) chunkoff[0] = 0;
  chunkoff[t+1] = scan[t];
}

// ---------------- K3: dense chunked render ----------------------------------
template<int USEPAD>
__global__ __launch_bounds__(256) void k_render3(
    const float* __restrict__ patch, const f4* __restrict__ pad4,
    const float* __restrict__ wbg, const float* __restrict__ shiftg,
    const float* __restrict__ boxp, const int* __restrict__ chunkoff,
    float* __restrict__ out)
{
  __shared__ float sp[256*16];     // all 256 (image,box) param records
  __shared__ float wl[NIMG*8];
  __shared__ float shl[NIMG];
  __shared__ int   coff[258];
  for (int i = threadIdx.x; i < 4096; i += 256) sp[i] = boxp[i];
  if (threadIdx.x < NIMG*8) wl[threadIdx.x] = wbg[threadIdx.x];
  if (threadIdx.x < NIMG)   shl[threadIdx.x] = shiftg[threadIdx.x];
  for (int i = threadIdx.x; i < 257; i += 256) coff[i] = chunkoff[i];
  __syncthreads();
  int total = coff[256];

  for (int chunk = blockIdx.x; chunk < total; chunk += RENDER_BLKS){
    // binary search: s = max{ s in [0,256) : coff[s] <= chunk }
    int lo = 0, hi = 255;
    #pragma unroll
    for (int it = 0; it < 8; it++){
      int mid = (lo + hi + 1) >> 1;
      if (coff[mid] <= chunk) lo = mid; else hi = mid - 1;
    }
    int s = lo;
    const float* bp = &sp[s*16];
    int d = (int)bp[2];
    int dd = d*d;
    int idx = (chunk - coff[s])*256 + (int)threadIdx.x;
    if (idx >= dd) continue;

    int b = s >> 4;
    float y0f = bp[0], x0f = bp[1];
    float cc = bp[5], ca = bp[6], sa = bp[7], top = bp[4];
    float ph1 = bp[13], sres = bp[8], delta = bp[9];

    int row = idx / d;
    int col = idx - row*d;
    int y = (int)y0f + row, x = (int)x0f + col;
    float yf = (float)y, xf = (float)x;
    float u = __fsub_rn(yf, y0f), v = __fsub_rn(xf, x0f);
    float um = __fsub_rn(u, cc), vm = __fsub_rn(v, cc);
    float iu = __fsub_rn(__fadd_rn(cc, __fmul_rn(ca, um)), __fmul_rn(sa, vm));
    float iv = __fadd_rn(__fadd_rn(cc, __fmul_rn(sa, um)), __fmul_rn(ca, vm));
    float py = __fsub_rn(iu, top), px = __fsub_rn(iv, top);
    if (!(py >= 0.0f && py <= ph1 && px >= 0.0f && px <= ph1)) continue;

    // winner check, only over precomputed window-overlapping boxes j>k
    uint32_t m = __float_as_uint(bp[14]);
    bool lose = false;
    while (m){
      int j = 31 - __clz(m);
      m &= ~(1u << j);
      const float* bq = &sp[((s & ~15) + j)*16];
      float u2 = __fsub_rn(yf, bq[0]);
      if (!(u2 >= 0.0f && u2 < bq[2])) continue;
      float v2 = __fsub_rn(xf, bq[1]);
      if (!(v2 >= 0.0f && v2 < bq[2])) continue;
      float um2 = __fsub_rn(u2, bq[5]), vm2 = __fsub_rn(v2, bq[5]);
      float iu2 = __fsub_rn(__fadd_rn(bq[5], __fmul_rn(bq[6], um2)), __fmul_rn(bq[7], vm2));
      float iv2 = __fadd_rn(__fadd_rn(bq[5], __fmul_rn(bq[7], um2)), __fmul_rn(bq[6], vm2));
      float py2 = __fsub_rn(iu2, bq[4]), px2 = __fsub_rn(iv2, bq[4]);
      if (py2 >= 0.0f && py2 <= bq[13] && px2 >= 0.0f && px2 <= bq[13]){ lose = true; break; }
    }
    if (lose) continue;

    float sy = __fsub_rn(__fmul_rn(__fadd_rn(py, 0.5f), sres), 0.5f);
    float sx = __fsub_rn(__fmul_rn(__fadd_rn(px, 0.5f), sres), 0.5f);
    float fy = floorf(sy), fx = floorf(sx);
    float wy = __fsub_rn(sy, fy), wx = __fsub_rn(sx, fx);
    int y0t = (int)fminf(fmaxf(fy, 0.0f), 639.0f);
    int y1t = (int)fminf(fmaxf(__fadd_rn(fy, 1.0f), 0.0f), 639.0f);
    int x0t = (int)fminf(fmaxf(fx, 0.0f), 639.0f);
    int x1t = (int)fminf(fmaxf(__fadd_rn(fx, 1.0f), 0.0f), 639.0f);
    float w00 = (1.0f-wy)*(1.0f-wx), w01 = (1.0f-wy)*wx;
    float w10 = wy*(1.0f-wx),        w11 = wy*wx;
    const float* wbb = &wl[b*8];
    float shf = shl[b];
    uint32_t n0 = __float_as_uint(bp[10]);
    uint32_t n1 = __float_as_uint(bp[11]);
    int pix = y*IMW + x;
    size_t base = (size_t)b*IMG_ELEMS + (size_t)pix*3;

    f4 p00, p01, p10, p11;
    int i00, i01, i10, i11;
    if constexpr (USEPAD){
      p00 = pad4[y0t*PSZ + x0t]; p01 = pad4[y0t*PSZ + x1t];
      p10 = pad4[y1t*PSZ + x0t]; p11 = pad4[y1t*PSZ + x1t];
      i00 = i01 = i10 = i11 = 0;
    } else {
      i00 = (y0t*PSZ + x0t)*3; i01 = (y0t*PSZ + x1t)*3;
      i10 = (y1t*PSZ + x0t)*3; i11 = (y1t*PSZ + x1t)*3;
    }
    #pragma unroll
    for (int c = 0; c < 3; c++){
      float wm = wbb[c], bd = wbb[3+c];
      float t00, t01, t10, t11;
      if constexpr (USEPAD){ t00 = p00[c]; t01 = p01[c]; t10 = p10[c]; t11 = p11[c]; }
      else { t00 = patch[i00+c]; t01 = patch[i01+c]; t10 = patch[i10+c]; t11 = patch[i11+c]; }
      float v00 = fminf(fmaxf(__fadd_rn(__fmul_rn(wm, t00), bd), -1.0f), 1.0f);
      v00 = fminf(fmaxf(__fadd_rn(v00, shf), -1.0f), 1.0f);
      float v01 = fminf(fmaxf(__fadd_rn(__fmul_rn(wm, t01), bd), -1.0f), 1.0f);
      v01 = fminf(fmaxf(__fadd_rn(v01, shf), -1.0f), 1.0f);
      float v10 = fminf(fmaxf(__fadd_rn(__fmul_rn(wm, t10), bd), -1.0f), 1.0f);
      v10 = fminf(fmaxf(__fadd_rn(v10, shf), -1.0f), 1.0f);
      float v11 = fminf(fmaxf(__fadd_rn(__fmul_rn(wm, t11), bd), -1.0f), 1.0f);
      v11 = fminf(fmaxf(__fadd_rn(v11, shf), -1.0f), 1.0f);
      float val = v00*w00 + v01*w01 + v10*w10 + v11*w11;
      float un = u01(rbits(n0, n1, (uint32_t)(pix*3 + c)));
      float span = __fsub_rn(0.01f, -0.01f);
      float nz = fmaxf(-0.01f, __fadd_rn(__fmul_rn(un, span), -0.01f));
      val = __fadd_rn(__fadd_rn(val, nz), delta);
      out[base + c] = fminf(fmaxf(val, -1.0f), 1.0f);
    }
  }
}

// ---------------- host launch ----------------
extern "C" void kernel_launch(void* const* d_in, const int* in_sizes, int n_in,
                              void* d_out, int out_size, void* d_ws, size_t ws_size,
                              hipStream_t stream){
  (void)in_sizes; (void)n_in; (void)out_size;
  const float* images = (const float*)d_in[0];
  const float* boxes  = (const float*)d_in[1];
  const float* patch  = (const float*)d_in[2];
  const float* scale  = (const float*)d_in[3];
  float* out = (float*)d_out;

  char* ws = (char*)d_ws;
  double* imgpart = (double*)(ws);               // 16*64*8 = 8192 B
  double* patpart = (double*)(ws + 8192);        // 8192 B
  float*  wb      = (float*)(ws + 16384);        // 512 B
  float*  shift   = (float*)(ws + 16896);        // 64 B
  float*  boxp    = (float*)(ws + 17408);        // 16384 B
  int*    chunkoff= (int*)(ws + 33792);          // 1032 B
  f4*     pad4    = (f4*)(ws + 65536);           // 640*640*16 = 6553600 B

  size_t need = 65536 + (size_t)PSZ*PSZ*16;
  int do_pad = (ws_size >= need) ? 1 : 0;

  hipLaunchKernelGGL(k_front, dim3(PATBLK + PADBLK + NIMG*ISUM), dim3(256), 0, stream,
                     images, patch, out, imgpart, patpart, pad4, do_pad);
  hipLaunchKernelGGL(k_final, dim3(1), dim3(256), 0, stream,
                     imgpart, patpart, shift, wb, boxp, chunkoff, boxes, scale);
  if (do_pad)
    hipLaunchKernelGGL(k_render3<1>, dim3(RENDER_BLKS), dim3(256), 0, stream,
                       patch, pad4, wb, shift, boxp, chunkoff, out);
  else
    hipLaunchKernelGGL(k_render3<0>, dim3(RENDER_BLKS), dim3(256), 0, stream,
                       patch, pad4, wb, shift, boxp, chunkoff, out);
}